// Round 6
// baseline (368.801 us; speedup 1.0000x reference)
//
#include <hip/hip_runtime.h>
#include <hip/hip_fp16.h>

#define NDIM 128     // OUT_DIM
#define KDIM 256     // IN_DIM
#define MT 10        // M-tiles (of 16 rows) per GEMM block -> 625 blocks
#define AROW 264     // LDS A-row stride in halfs (16B-aligned, breaks pow2)
#define CHUNK 6400   // edges per phase1/phase3 block
#define MAXBUCK 128  // LDS histogram capacity (buckets = N/1024 <= 128)
#define SCAP 24576   // staged tgt capacity in k_fine LDS (96 KB)

typedef _Float16 half8 __attribute__((ext_vector_type(8)));
typedef _Float16 half4t __attribute__((ext_vector_type(4)));
typedef float float4v __attribute__((ext_vector_type(4)));

// ---------- Wc = Wg @ Wp, written directly in MFMA B-fragment layout (fp16)
// Bfrag[((ntile*8 + kk)*64 + lane)*8 + j] = Wc[n][k],
//   n = ntile*16 + (lane&15), k = kk*32 + (lane>>4)*8 + j
__global__ void k_combine_w(const float* __restrict__ Wp, const float* __restrict__ Wg,
                            _Float16* __restrict__ Bfrag) {
    int o = blockIdx.x;      // n: 0..127
    int i = threadIdx.x;     // k: 0..255
    float acc = 0.f;
#pragma unroll 4
    for (int k = 0; k < 128; ++k) acc = fmaf(Wg[o * 128 + k], Wp[k * 256 + i], acc);
    int kk = i >> 5, r = i & 31, quad = r >> 3, j = r & 7;
    int ntile = o >> 4, lanen = o & 15, lane = quad * 16 + lanen;
    Bfrag[(((ntile * 8 + kk) * 64) + lane) * 8 + j] = (_Float16)acc;
}

// ---------- CSR build, pass 1: per-block coarse histogram (bucket = tgt>>10)
__global__ __launch_bounds__(256) void k_phase1(const int* __restrict__ col, int E,
                                                int* __restrict__ hist, int NBLK, int NBUCK) {
    __shared__ int h[MAXBUCK];
    int tid = threadIdx.x;
    if (tid < MAXBUCK) h[tid] = 0;
    __syncthreads();
    int e0 = blockIdx.x * CHUNK;
    int e1 = min(e0 + CHUNK, E);
    for (int e = e0 + tid; e < e1; e += 256) atomicAdd(&h[col[e] >> 10], 1);
    __syncthreads();
    if (tid < NBUCK) hist[tid * NBLK + blockIdx.x] = h[tid];
}

// ---------- CSR build, pass 2: in-place exclusive scan of hist (bucket-major)
__global__ __launch_bounds__(1024) void k_scan2(int* __restrict__ hist, int NE) {
    __shared__ int s[1024];
    int t = threadIdx.x;
    int CH = (NE + 1023) >> 10;
    int off = t * CH;
    int sum = 0;
    for (int j = 0; j < CH; ++j) { int idx = off + j; if (idx < NE) sum += hist[idx]; }
    s[t] = sum;
    __syncthreads();
    for (int d = 1; d < 1024; d <<= 1) {
        int y = (t >= d) ? s[t - d] : 0;
        __syncthreads();
        s[t] += y;
        __syncthreads();
    }
    int run = s[t] - sum;   // exclusive prefix of this thread's range
    for (int j = 0; j < CH; ++j) {
        int idx = off + j;
        if (idx < NE) { int v = hist[idx]; hist[idx] = run; run += v; }
    }
}

// ---------- CSR build, pass 3: scatter src/tgt (SoA) into per-(bucket,block) runs
__global__ __launch_bounds__(256) void k_phase3(const int* __restrict__ ei, int E,
                                                const int* __restrict__ offs, int NBLK, int NBUCK,
                                                int* __restrict__ tmpS, int* __restrict__ tmpT) {
    __shared__ int cur[MAXBUCK];
    int tid = threadIdx.x;
    if (tid < NBUCK) cur[tid] = offs[tid * NBLK + blockIdx.x];
    __syncthreads();
    int e0 = blockIdx.x * CHUNK;
    int e1 = min(e0 + CHUNK, E);
    for (int e = e0 + tid; e < e1; e += 256) {
        int r = ei[e];          // source
        int c = ei[E + e];      // target
        int p = atomicAdd(&cur[c >> 10], 1);
        tmpS[p] = r;
        tmpT[p] = c;
    }
}

// ---------- CSR build, pass 4: per-bucket fine counting sort (1024 nodes/bucket)
// tgt list staged in LDS so the scatter pass re-reads LDS, not global.
__global__ __launch_bounds__(1024) void k_fine(const int* __restrict__ tmpS,
                                               const int* __restrict__ tmpT,
                                               const int* __restrict__ offs, int NBLK, int NBUCK,
                                               int N, int E,
                                               int* __restrict__ sortedRow,
                                               int* __restrict__ cnt,
                                               int* __restrict__ rowStart) {
    __shared__ int scnt[1024];
    __shared__ int cur[1024];
    __shared__ int stg[SCAP];
    int b = blockIdx.x;
    int t = threadIdx.x;
    int nodeBase = b << 10;
    int start = offs[b * NBLK];
    int end = (b + 1 < NBUCK) ? offs[(b + 1) * NBLK] : E;
    int len = end - start;
    int nst = min(len, SCAP);

    scnt[t] = 0;
    __syncthreads();
    for (int j = t; j < nst; j += 1024) {
        int tg = tmpT[start + j];
        stg[j] = tg;
        atomicAdd(&scnt[tg - nodeBase], 1);
    }
    for (int j = nst + t; j < len; j += 1024)            // overflow path (never for this dist)
        atomicAdd(&scnt[tmpT[start + j] - nodeBase], 1);
    __syncthreads();
    int v = scnt[t];
    for (int d = 1; d < 1024; d <<= 1) {                 // inclusive scan
        int y = (t >= d) ? scnt[t - d] : 0;
        __syncthreads();
        scnt[t] += y;
        __syncthreads();
    }
    int excl = scnt[t] - v;
    int node = nodeBase + t;
    if (node < N) {
        cnt[node] = v;
        rowStart[node] = start + excl;
    }
    cur[t] = start + excl;
    __syncthreads();
    for (int j = t; j < nst; j += 1024) {
        int tg = stg[j];
        int src = tmpS[start + j];
        int slot = atomicAdd(&cur[tg - nodeBase], 1);
        sortedRow[slot] = src;
    }
    for (int j = nst + t; j < len; j += 1024) {
        int tg = tmpT[start + j];
        int src = tmpS[start + j];
        int slot = atomicAdd(&cur[tg - nodeBase], 1);
        sortedRow[slot] = src;
    }
    if (b == NBUCK - 1 && t == 0) rowStart[N] = E;
}

// ---------- g = fp16( dinv * (x @ Wc^T) ) via MFMA 16x16x32 f16, double-buffered LDS
__global__ __launch_bounds__(256) void k_gemm_mfma(const float* __restrict__ x,
                                                   const _Float16* __restrict__ Bfrag,
                                                   const int* __restrict__ cnt,
                                                   _Float16* __restrict__ g, int nrows) {
    __shared__ __align__(16) _Float16 xs[2][16 * AROW];
    int tid  = threadIdx.x;
    int lane = tid & 63;
    int w    = tid >> 6;      // wave 0..3
    int quad = lane >> 4;
    int lcol = lane & 15;
    int m_   = tid >> 6;      // staging row group
    (void)m_;

    const half8* Bv = (const half8*)Bfrag;
    half8 b0[8], b1[8];
#pragma unroll
    for (int kk = 0; kk < 8; ++kk) {
        b0[kk] = Bv[(w * 8 + kk) * 64 + lane];
        b1[kk] = Bv[((w + 4) * 8 + kk) * 64 + lane];
    }

    long base = (long)blockIdx.x * (16 * MT);
    int sm = tid >> 6;          // unused helper
    (void)sm;

    // prologue: load tile 0
    float4 v[4];
    {
        const float4* xv = (const float4*)(x + base * KDIM);
#pragma unroll
        for (int ii = 0; ii < 4; ++ii) v[ii] = xv[tid + ii * 256];
#pragma unroll
        for (int ii = 0; ii < 4; ++ii) {
            int idx = tid + ii * 256;
            int m = idx >> 6, k4 = idx & 63;
            half4t h; h[0] = (_Float16)v[ii].x; h[1] = (_Float16)v[ii].y;
            h[2] = (_Float16)v[ii].z; h[3] = (_Float16)v[ii].w;
            *(half4t*)&xs[0][m * AROW + k4 * 4] = h;
        }
    }
    __syncthreads();

    for (int t = 0; t < MT; ++t) {
        int curb = t & 1, nxtb = curb ^ 1;
        long m0 = base + t * 16;
        if (t + 1 < MT) {
            const float4* xn = (const float4*)(x + (m0 + 16) * KDIM);
#pragma unroll
            for (int ii = 0; ii < 4; ++ii) v[ii] = xn[tid + ii * 256];
        }

        float4v acc0 = {0.f, 0.f, 0.f, 0.f}, acc1 = {0.f, 0.f, 0.f, 0.f};
#pragma unroll
        for (int kk = 0; kk < 8; ++kk) {
            half8 a = *(const half8*)(&xs[curb][lcol * AROW + kk * 32 + quad * 8]);
            acc0 = __builtin_amdgcn_mfma_f32_16x16x32_f16(a, b0[kk], acc0, 0, 0, 0);
            acc1 = __builtin_amdgcn_mfma_f32_16x16x32_f16(a, b1[kk], acc1, 0, 0, 0);
        }

        // C/D layout: col = lane&15, row = quad*4 + reg
#pragma unroll
        for (int r = 0; r < 4; ++r) {
            long node = m0 + quad * 4 + r;
            float di = rsqrtf((float)(cnt[node] + 1));   // deg = cnt + self-loop
            g[node * NDIM + w * 16 + lcol]        = (_Float16)(acc0[r] * di);
            g[node * NDIM + (w + 4) * 16 + lcol]  = (_Float16)(acc1[r] * di);
        }

        if (t + 1 < MT) {
#pragma unroll
            for (int ii = 0; ii < 4; ++ii) {
                int idx = tid + ii * 256;
                int m = idx >> 6, k4 = idx & 63;
                half4t h; h[0] = (_Float16)v[ii].x; h[1] = (_Float16)v[ii].y;
                h[2] = (_Float16)v[ii].z; h[3] = (_Float16)v[ii].w;
                *(half4t*)&xs[nxtb][m * AROW + k4 * 4] = h;
            }
        }
        __syncthreads();
    }
}

// ---------- gather + scale + bias + row L2-normalize (one WAVE per node, unroll 8)
__global__ __launch_bounds__(256) void k_gather(const __half2* __restrict__ g,
                                                const int* __restrict__ rowStart,
                                                const int* __restrict__ sortedRow,
                                                const int* __restrict__ cnt,
                                                const float* __restrict__ bg,
                                                float* __restrict__ out) {
    int lane = threadIdx.x & 63;
    int i = blockIdx.x * 4 + (threadIdx.x >> 6);   // node, N divisible by 4
    const int s = rowStart[i];
    const int e = rowStart[i + 1];
    const size_t stride = NDIM / 2;                 // 64 half2 per row

    __half2 self = g[(size_t)i * stride + lane];
    float ax = __low2float(self), ay = __high2float(self);

    int p = s;
    for (; p + 8 <= e; p += 8) {
        int r0 = sortedRow[p + 0];
        int r1 = sortedRow[p + 1];
        int r2 = sortedRow[p + 2];
        int r3 = sortedRow[p + 3];
        int r4 = sortedRow[p + 4];
        int r5 = sortedRow[p + 5];
        int r6 = sortedRow[p + 6];
        int r7 = sortedRow[p + 7];
        __half2 m0 = g[(size_t)r0 * stride + lane];
        __half2 m1 = g[(size_t)r1 * stride + lane];
        __half2 m2 = g[(size_t)r2 * stride + lane];
        __half2 m3 = g[(size_t)r3 * stride + lane];
        __half2 m4 = g[(size_t)r4 * stride + lane];
        __half2 m5 = g[(size_t)r5 * stride + lane];
        __half2 m6 = g[(size_t)r6 * stride + lane];
        __half2 m7 = g[(size_t)r7 * stride + lane];
        ax += __low2float(m0) + __low2float(m1) + __low2float(m2) + __low2float(m3)
            + __low2float(m4) + __low2float(m5) + __low2float(m6) + __low2float(m7);
        ay += __high2float(m0) + __high2float(m1) + __high2float(m2) + __high2float(m3)
            + __high2float(m4) + __high2float(m5) + __high2float(m6) + __high2float(m7);
    }
    for (; p < e; ++p) {
        int r = sortedRow[p];
        __half2 m = g[(size_t)r * stride + lane];
        ax += __low2float(m);
        ay += __high2float(m);
    }

    float di = rsqrtf((float)(cnt[i] + 1));
    float2 b = ((const float2*)bg)[lane];
    float v0 = fmaf(di, ax, b.x);
    float v1 = fmaf(di, ay, b.y);

    float sq = v0 * v0 + v1 * v1;
#pragma unroll
    for (int d = 32; d > 0; d >>= 1) sq += __shfl_xor(sq, d);
    float scale = 1.0f / fmaxf(sqrtf(sq), 1e-12f);
    ((float2*)out)[(size_t)i * stride + lane] = make_float2(v0 * scale, v1 * scale);
}

extern "C" void kernel_launch(void* const* d_in, const int* in_sizes, int n_in,
                              void* d_out, int out_size, void* d_ws, size_t ws_size,
                              hipStream_t stream) {
    const float* x  = (const float*)d_in[0];
    const int*   ei = (const int*)  d_in[1];
    const float* Wp = (const float*)d_in[2];
    const float* Wg = (const float*)d_in[3];
    const float* bg = (const float*)d_in[4];
    float* out = (float*)d_out;

    const int N = in_sizes[0] / KDIM;   // 100000
    const int E = in_sizes[1] / 2;      // 1600000

    const int NBLK  = (E + CHUNK - 1) / CHUNK;   // 250
    const int NBUCK = (N + 1023) >> 10;          // 98
    const int NE    = NBLK * NBUCK;              // 24500

    // carve workspace (256B aligned)
    char* p = (char*)d_ws;
    auto carve = [&](size_t bytes) { void* r = (void*)p; p += (bytes + 255) & ~(size_t)255; return r; };
    _Float16* g      = (_Float16*)carve((size_t)N * NDIM * 2);  // 25.6 MB
    int*   sortedRow = (int*)  carve((size_t)E * 4);            // 6.4 MB
    int*   tmpS      = (int*)  carve((size_t)E * 4);            // 6.4 MB
    int*   tmpT      = (int*)  carve((size_t)E * 4);            // 6.4 MB
    _Float16* Bfrag  = (_Float16*)carve((size_t)KDIM * NDIM * 2);
    int*   cnt       = (int*)  carve((size_t)N * 4);
    int*   rowStart  = (int*)  carve((size_t)(N + 1) * 4);
    int*   hist      = (int*)  carve((size_t)NE * 4);

    hipLaunchKernelGGL(k_combine_w, dim3(NDIM), dim3(KDIM), 0, stream, Wp, Wg, Bfrag);
    hipLaunchKernelGGL(k_phase1, dim3(NBLK), dim3(256), 0, stream, ei + E, E, hist, NBLK, NBUCK);
    hipLaunchKernelGGL(k_scan2, dim3(1), dim3(1024), 0, stream, hist, NE);
    hipLaunchKernelGGL(k_phase3, dim3(NBLK), dim3(256), 0, stream, ei, E, hist, NBLK, NBUCK, tmpS, tmpT);
    hipLaunchKernelGGL(k_fine, dim3(NBUCK), dim3(1024), 0, stream, tmpS, tmpT, hist, NBLK, NBUCK,
                       N, E, sortedRow, cnt, rowStart);
    hipLaunchKernelGGL(k_gemm_mfma, dim3(N / (16 * MT)), dim3(256), 0, stream, x, Bfrag, cnt, g, N);
    hipLaunchKernelGGL(k_gather, dim3(N / 4), dim3(256), 0, stream,
                       (const __half2*)g, rowStart, sortedRow, cnt, bg, out);
}